// Round 4
// baseline (331.522 us; speedup 1.0000x reference)
//
#include <hip/hip_runtime.h>
#include <hip/hip_bf16.h>
#include <math.h>

typedef __bf16 bf16x8 __attribute__((ext_vector_type(8)));
typedef float f32x4 __attribute__((ext_vector_type(4)));
typedef __hip_bfloat16 bf16_t;

#define MFMA_BF16(a, b, c) __builtin_amdgcn_mfma_f32_16x16x32_bf16((a), (b), (c), 0, 0, 0)

// async global->LDS, 16B per lane; LDS dest = wave-uniform base + lane*16
__device__ __forceinline__ void async_copy16(const bf16_t* g, bf16_t* lds_base) {
  __builtin_amdgcn_global_load_lds(
      (const __attribute__((address_space(1))) unsigned int*)g,
      (__attribute__((address_space(3))) unsigned int*)lds_base,
      16, 0, 0);
}

__device__ __forceinline__ unsigned fbits(float x) { return __builtin_bit_cast(unsigned, x); }

// ---------------- cast f32 -> bf16 (vectorized) ----------------
__global__ void cast_f32_to_bf16(const float* __restrict__ in, bf16_t* __restrict__ out, int n4) {
  int i = blockIdx.x * blockDim.x + threadIdx.x;
  if (i < n4) {
    float4 v = ((const float4*)in)[i];
    union { bf16_t h[4]; ushort4 u; } cv;
    cv.h[0] = __float2bfloat16(v.x);
    cv.h[1] = __float2bfloat16(v.y);
    cv.h[2] = __float2bfloat16(v.z);
    cv.h[3] = __float2bfloat16(v.w);
    ((ushort4*)out)[i] = cv.u;
  }
}

// bqkv[3072] = {bq*qscale (2048), bk (512), bv (512)}
__global__ void concat_bias3(const float* __restrict__ bq, const float* __restrict__ bk,
                             const float* __restrict__ bv, float* __restrict__ dst, float qscale) {
  int i = blockIdx.x * blockDim.x + threadIdx.x;  // 3072
  float v;
  if (i < 2048) v = bq[i] * qscale;
  else if (i < 2560) v = bk[i - 2048];
  else v = bv[i - 2560];
  dst[i] = v;
}

// ---------------- strided transpose + cast -> bf16 (with scale) ----------------
// in (z,r,c) at in[z*in_bs + r*in_rs + c] -> out (z,c,r) at out[z*out_bs + c*R + r]
template <typename TIN>
__global__ void transpose_to_bf16(const TIN* __restrict__ in, bf16_t* __restrict__ out,
                                  int R, int C, int in_rs, size_t in_bs, size_t out_bs,
                                  float scale) {
  __shared__ float tile[32][33];
  in += (size_t)blockIdx.z * in_bs;
  out += (size_t)blockIdx.z * out_bs;
  const int c0 = blockIdx.x * 32, r0 = blockIdx.y * 32;
  const int tx = threadIdx.x, ty = threadIdx.y;
#pragma unroll
  for (int i = ty; i < 32; i += 8)
    tile[i][tx] = (float)in[(size_t)(r0 + i) * in_rs + c0 + tx];
  __syncthreads();
#pragma unroll
  for (int i = ty; i < 32; i += 8)
    out[(size_t)(c0 + i) * R + r0 + tx] = __float2bfloat16(tile[tx][i] * scale);
}

// ---------------- GEMM: C[M,N] = A[M,K] @ Bt[N,K]^T + bias ----------------
template <typename TOUT>
__global__ __launch_bounds__(256, 2) void gemm_bt(
    const bf16_t* __restrict__ A, const bf16_t* __restrict__ Bt,
    const float* __restrict__ bias, TOUT* __restrict__ C,
    int M, int N, int K) {
  __shared__ alignas(16) bf16_t As[128 * 32];
  __shared__ alignas(16) bf16_t Bs[128 * 32];

  const int tid = threadIdx.x;
  const int w = tid >> 6, lane = tid & 63;
  const int quad = lane >> 4, l16 = lane & 15;
  const int wm = w >> 1, wn = w & 1;
  const int m0 = blockIdx.y * 128, n0 = blockIdx.x * 128;

  f32x4 acc[4][4] = {};

  const int srow = lane >> 2;
  const int scol = (lane & 3) * 8;

  for (int k0 = 0; k0 < K; k0 += 32) {
#pragma unroll
    for (int c = 0; c < 2; ++c) {
      const int r = w * 32 + c * 16 + srow;
      async_copy16(A + (size_t)(m0 + r) * K + k0 + scol, &As[(w * 32 + c * 16) * 32]);
      async_copy16(Bt + (size_t)(n0 + r) * K + k0 + scol, &Bs[(w * 32 + c * 16) * 32]);
    }
    __syncthreads();

    bf16x8 af[4], bf[4];
#pragma unroll
    for (int i = 0; i < 4; ++i) {
      af[i] = *(const bf16x8*)&As[(wm * 64 + i * 16 + l16) * 32 + quad * 8];
      bf[i] = *(const bf16x8*)&Bs[(wn * 64 + i * 16 + l16) * 32 + quad * 8];
    }
#pragma unroll
    for (int i = 0; i < 4; ++i)
#pragma unroll
      for (int j = 0; j < 4; ++j)
        acc[i][j] = MFMA_BF16(af[i], bf[j], acc[i][j]);
    __syncthreads();
  }

#pragma unroll
  for (int i = 0; i < 4; ++i) {
    const int row = m0 + wm * 64 + i * 16 + quad * 4;
#pragma unroll
    for (int j = 0; j < 4; ++j) {
      const int col = n0 + wn * 64 + j * 16 + l16;
      const float bv = bias[col];
#pragma unroll
      for (int r = 0; r < 4; ++r) {
        const float val = acc[i][j][r] + bv;
        if constexpr (__is_same(TOUT, float)) {
          C[(size_t)(row + r) * N + col] = val;
        } else {
          C[(size_t)(row + r) * N + col] = __float2bfloat16(val);
        }
      }
    }
  }
}

// ---------------- GQA flash attention (v4: 256q/block, 64q/wave) ----------------
// QKV: [B*S][3072] bf16 (q at col h*64, Wq pre-scaled by 0.125*log2e; k at 2048+g*64; v at 2560+g*64)
// VT: [B*512][2048] bf16 (row b*512+g*64+d, col s); O: [B*S][2048] bf16
// grid (S/256, NH, B) = 512 blocks = 2/CU; 256 threads; wave owns 64 q rows (4 mt tiles).
// LDS tiles: 64-elem rows, 16B chunks XOR-swizzled: phys_chunk = chunk ^ (row&7).
__global__ __launch_bounds__(256, 2) void gqa_attn(
    const bf16_t* __restrict__ QKV, const bf16_t* __restrict__ VT, bf16_t* __restrict__ O) {
  constexpr int S = 2048, HID = 2048, QKVS = 3072, HD = 64;
  const int tid = threadIdx.x;
  const int w = tid >> 6, lane = tid & 63;
  const int quad = lane >> 4, l16 = lane & 15;
  const int q0 = blockIdx.x * 256;
  const int h = blockIdx.y, b = blockIdx.z;
  const int g = h >> 2;  // rep = 4

  __shared__ alignas(16) bf16_t Ks[64 * 64];
  __shared__ alignas(16) bf16_t VTs[64 * 64];
  __shared__ alignas(16) bf16_t Ps[256 * 64];

  // Q fragments in registers (B-operand layout: n=l16 -> q, k=quad*8+j); already scaled
  bf16x8 qf[4][2];
#pragma unroll
  for (int mt = 0; mt < 4; ++mt)
#pragma unroll
    for (int ks = 0; ks < 2; ++ks)
      qf[mt][ks] = *(const bf16x8*)&QKV[(size_t)(b * S + q0 + w * 64 + mt * 16 + l16) * QKVS +
                                        h * HD + ks * 32 + quad * 8];

  const int rr = lane >> 3, c7 = lane & 7;
  const int scol = (c7 ^ rr) * 8;  // swizzled SOURCE column so LDS dest lands swizzled
  const int sx = l16 & 7;

  const bf16_t* Kbase = QKV + (size_t)b * S * QKVS + 2048 + g * HD;
  const bf16_t* Vbase = VT + (size_t)(b * 512 + g * HD) * S;

  f32x4 oacc[4][4] = {};
  f32x4 lacc[4] = {};
  bf16x8 ones;
#pragma unroll
  for (int j = 0; j < 8; ++j) ones[j] = (__bf16)1.0f;

  for (int s0 = 0; s0 < S; s0 += 64) {
    __syncthreads();
#pragma unroll
    for (int cg = 0; cg < 2; ++cg) {
      const int r = w * 16 + cg * 8 + rr;
      async_copy16(Kbase + (size_t)(s0 + r) * QKVS + scol, &Ks[(w * 16 + cg * 8) * 64]);
      async_copy16(Vbase + (size_t)r * S + s0 + scol, &VTs[(w * 16 + cg * 8) * 64]);
    }
    __syncthreads();

    // ---- S^T = K·Q^T (row=kv=quad*4+r, col=q=l16); p=exp2(s); pack(trunc) -> Ps[q][kv] ----
#pragma unroll
    for (int nt = 0; nt < 4; ++nt) {
      bf16x8 kf0 = *(const bf16x8*)&Ks[(nt * 16 + l16) * 64 + ((quad ^ sx) * 8)];
      bf16x8 kf1 = *(const bf16x8*)&Ks[(nt * 16 + l16) * 64 + (((4 + quad) ^ sx) * 8)];
#pragma unroll
      for (int mt = 0; mt < 4; ++mt) {
        f32x4 s = {};
        s = MFMA_BF16(kf0, qf[mt][0], s);
        s = MFMA_BF16(kf1, qf[mt][1], s);
        const float p0 = __builtin_amdgcn_exp2f(s[0]);
        const float p1 = __builtin_amdgcn_exp2f(s[1]);
        const float p2 = __builtin_amdgcn_exp2f(s[2]);
        const float p3 = __builtin_amdgcn_exp2f(s[3]);
        uint2 pk;
        pk.x = __builtin_amdgcn_perm(fbits(p1), fbits(p0), 0x07060302);  // [bf16(p1)|bf16(p0)]
        pk.y = __builtin_amdgcn_perm(fbits(p3), fbits(p2), 0x07060302);
        // logical col = nt*16 + quad*4 (+r): chunk = nt*2+(quad>>1), in-chunk off = (quad&1)*4
        *(uint2*)&Ps[(w * 64 + mt * 16 + l16) * 64 +
                     (((nt * 2 + (quad >> 1)) ^ sx) * 8) + (quad & 1) * 4] = pk;
      }
    }

    // ---- O += P·V; row-sums via ones-B MFMA (sums truncated bf16 P -> bias cancels) ----
#pragma unroll
    for (int kc = 0; kc < 2; ++kc) {
      bf16x8 pf[4];
#pragma unroll
      for (int mt = 0; mt < 4; ++mt) {
        pf[mt] = *(const bf16x8*)&Ps[(w * 64 + mt * 16 + l16) * 64 + (((kc * 4 + quad) ^ sx) * 8)];
        lacc[mt] = MFMA_BF16(pf[mt], ones, lacc[mt]);
      }
#pragma unroll
      for (int dt = 0; dt < 4; ++dt) {
        bf16x8 vf = *(const bf16x8*)&VTs[(dt * 16 + l16) * 64 + (((kc * 4 + quad) ^ sx) * 8)];
#pragma unroll
        for (int mt = 0; mt < 4; ++mt)
          oacc[mt][dt] = MFMA_BF16(pf[mt], vf, oacc[mt][dt]);
      }
    }
  }

  // ---- normalize + store; lacc[mt][r] is lsum for q=mt*16+quad*4+r (same rows as oacc) ----
#pragma unroll
  for (int mt = 0; mt < 4; ++mt) {
    float linv[4];
#pragma unroll
    for (int r = 0; r < 4; ++r) linv[r] = 1.0f / lacc[mt][r];
#pragma unroll
    for (int dt = 0; dt < 4; ++dt)
#pragma unroll
      for (int r = 0; r < 4; ++r)
        O[(size_t)(b * S + q0 + w * 64 + mt * 16 + quad * 4 + r) * HID + h * HD + dt * 16 + l16] =
            __float2bfloat16(oacc[mt][dt][r] * linv[r]);
  }
}

extern "C" void kernel_launch(void* const* d_in, const int* in_sizes, int n_in,
                              void* d_out, int out_size, void* d_ws, size_t ws_size,
                              hipStream_t stream) {
  const float* hidden = (const float*)d_in[0];
  const float* Wq = (const float*)d_in[1];
  const float* bq = (const float*)d_in[2];
  const float* Wk = (const float*)d_in[3];
  const float* bk = (const float*)d_in[4];
  const float* Wv = (const float*)d_in[5];
  const float* bv = (const float*)d_in[6];
  const float* Wo = (const float*)d_in[7];
  const float* bo = (const float*)d_in[8];
  float* out = (float*)d_out;

  constexpr int B = 2, S = 2048, HID = 2048, KV = 512, QKVN = 3072;
  constexpr int M = B * S;  // 4096
  const float c1 = 0.125f * 1.44269504089f;

  char* ws = (char*)d_ws;
  bf16_t* hiddenB = (bf16_t*)ws; ws += (size_t)M * HID * 2;
  bf16_t* WqkvT = (bf16_t*)ws;   ws += (size_t)QKVN * HID * 2;
  bf16_t* WoT = (bf16_t*)ws;     ws += (size_t)HID * HID * 2;
  bf16_t* qkv = (bf16_t*)ws;     ws += (size_t)M * QKVN * 2;
  bf16_t* vT = (bf16_t*)ws;      ws += (size_t)M * KV * 2;
  bf16_t* attn = (bf16_t*)ws;    ws += (size_t)M * HID * 2;
  float* bqkv = (float*)ws;      ws += QKVN * 4;

  dim3 tb(32, 8);
  cast_f32_to_bf16<<<(M * HID / 4 + 255) / 256, 256, 0, stream>>>(hidden, hiddenB, M * HID / 4);
  // WqkvT rows: [0,2048) = Wq^T * c1, [2048,2560) = Wk^T, [2560,3072) = Wv^T
  transpose_to_bf16<float><<<dim3(64, 64, 1), tb, 0, stream>>>(Wq, WqkvT, HID, HID, HID, 0, 0, c1);
  transpose_to_bf16<float><<<dim3(16, 64, 1), tb, 0, stream>>>(
      Wk, WqkvT + (size_t)2048 * HID, HID, KV, KV, 0, 0, 1.0f);
  transpose_to_bf16<float><<<dim3(16, 64, 1), tb, 0, stream>>>(
      Wv, WqkvT + (size_t)2560 * HID, HID, KV, KV, 0, 0, 1.0f);
  transpose_to_bf16<float><<<dim3(64, 64, 1), tb, 0, stream>>>(Wo, WoT, HID, HID, HID, 0, 0, 1.0f);
  concat_bias3<<<QKVN / 256, 256, 0, stream>>>(bq, bk, bv, bqkv, c1);

  gemm_bt<bf16_t><<<dim3(QKVN / 128, M / 128), 256, 0, stream>>>(hiddenB, WqkvT, bqkv, qkv, M, QKVN, HID);

  // v = qkv[:, 2560:3072]: [b][s][512] -> vT [b][512][2048]
  transpose_to_bf16<bf16_t><<<dim3(16, 64, 2), tb, 0, stream>>>(
      qkv + 2560, vT, S, KV, QKVN, (size_t)S * QKVN, (size_t)KV * S, 1.0f);

  gqa_attn<<<dim3(S / 256, 32, B), 256, 0, stream>>>(qkv, vT, attn);

  gemm_bt<float><<<dim3(HID / 128, M / 128), 256, 0, stream>>>(attn, WoT, bo, out, M, HID, HID);
}

// Round 5
// 323.485 us; speedup vs baseline: 1.0248x; 1.0248x over previous
//
#include <hip/hip_runtime.h>
#include <hip/hip_bf16.h>
#include <math.h>

typedef __bf16 bf16x8 __attribute__((ext_vector_type(8)));
typedef float f32x4 __attribute__((ext_vector_type(4)));
typedef __hip_bfloat16 bf16_t;

#define MFMA_BF16(a, b, c) __builtin_amdgcn_mfma_f32_16x16x32_bf16((a), (b), (c), 0, 0, 0)

// async global->LDS, 16B per lane; LDS dest = wave-uniform base + lane*16
__device__ __forceinline__ void async_copy16(const bf16_t* g, bf16_t* lds_base) {
  __builtin_amdgcn_global_load_lds(
      (const __attribute__((address_space(1))) unsigned int*)g,
      (__attribute__((address_space(3))) unsigned int*)lds_base,
      16, 0, 0);
}

__device__ __forceinline__ unsigned fbits(float x) { return __builtin_bit_cast(unsigned, x); }

// ---------------- fused prep: cast hidden, transpose 4 weights, concat bias ----------------
// block ranges: [0,8192) cast; [8192,12288) Wq^T*c1; [12288,13312) Wk^T; [13312,14336) Wv^T;
// [14336,18432) Wo^T; [18432,18444) bias concat. 256 threads.
__global__ __launch_bounds__(256) void prep(
    const float* __restrict__ hidden, const float* __restrict__ Wq, const float* __restrict__ Wk,
    const float* __restrict__ Wv, const float* __restrict__ Wo,
    const float* __restrict__ bq, const float* __restrict__ bk, const float* __restrict__ bv,
    bf16_t* __restrict__ hiddenB, bf16_t* __restrict__ WqkvT, bf16_t* __restrict__ WoT,
    float* __restrict__ bqkv, float c1) {
  __shared__ float tile[32][33];
  int bid = blockIdx.x;
  const int t = threadIdx.x;
  if (bid < 8192) {  // cast hidden f32 -> bf16, float4 per thread
    const int i = bid * 256 + t;
    float4 v = ((const float4*)hidden)[i];
    union { bf16_t h[4]; ushort4 u; } cv;
    cv.h[0] = __float2bfloat16(v.x);
    cv.h[1] = __float2bfloat16(v.y);
    cv.h[2] = __float2bfloat16(v.z);
    cv.h[3] = __float2bfloat16(v.w);
    ((ushort4*)hiddenB)[i] = cv.u;
    return;
  }
  bid -= 8192;
  if (bid >= 10240) {  // bias concat: 12 blocks x 256 = 3072
    const int i = (bid - 10240) * 256 + t;
    float v;
    if (i < 2048) v = bq[i] * c1;
    else if (i < 2560) v = bk[i - 2048];
    else v = bv[i - 2560];
    bqkv[i] = v;
    return;
  }
  // weight transpose: in [2048][C] -> out [C][2048], 32x32 tiles
  const float* src;
  bf16_t* dst;
  int Cc, bx, by;
  float scale = 1.0f;
  if (bid < 4096) { src = Wq; dst = WqkvT; Cc = 2048; bx = bid & 63; by = bid >> 6; scale = c1; }
  else if (bid < 5120) { bid -= 4096; src = Wk; dst = WqkvT + (size_t)2048 * 2048; Cc = 512; bx = bid & 15; by = bid >> 4; }
  else if (bid < 6144) { bid -= 5120; src = Wv; dst = WqkvT + (size_t)2560 * 2048; Cc = 512; bx = bid & 15; by = bid >> 4; }
  else { bid -= 6144; src = Wo; dst = WoT; Cc = 2048; bx = bid & 63; by = bid >> 6; }
  const int tx = t & 31, ty = t >> 5;
  const int c0 = bx * 32, r0 = by * 32;
#pragma unroll
  for (int i = ty; i < 32; i += 8)
    tile[i][tx] = src[(size_t)(r0 + i) * Cc + c0 + tx];
  __syncthreads();
#pragma unroll
  for (int i = ty; i < 32; i += 8)
    dst[(size_t)(c0 + i) * 2048 + r0 + tx] = __float2bfloat16(tile[tx][i] * scale);
}

// ---------------- GEMM: C[M,N] = A[M,K] @ Bt[N,K]^T + bias ----------------
// If vTp != nullptr, blocks with n0 >= 2560 write vT[b][col-2560][s] instead of C
// (v-columns of the QKV projection go straight to the transposed layout attention needs).
template <typename TOUT>
__global__ __launch_bounds__(256, 2) void gemm_bt(
    const bf16_t* __restrict__ A, const bf16_t* __restrict__ Bt,
    const float* __restrict__ bias, TOUT* __restrict__ C, bf16_t* __restrict__ vTp,
    int M, int N, int K) {
  __shared__ alignas(16) bf16_t As[128 * 32];
  __shared__ alignas(16) bf16_t Bs[128 * 32];

  const int tid = threadIdx.x;
  const int w = tid >> 6, lane = tid & 63;
  const int quad = lane >> 4, l16 = lane & 15;
  const int wm = w >> 1, wn = w & 1;
  const int m0 = blockIdx.y * 128, n0 = blockIdx.x * 128;

  f32x4 acc[4][4] = {};

  const int srow = lane >> 2;
  const int scol = (lane & 3) * 8;

  for (int k0 = 0; k0 < K; k0 += 32) {
#pragma unroll
    for (int c = 0; c < 2; ++c) {
      const int r = w * 32 + c * 16 + srow;
      async_copy16(A + (size_t)(m0 + r) * K + k0 + scol, &As[(w * 32 + c * 16) * 32]);
      async_copy16(Bt + (size_t)(n0 + r) * K + k0 + scol, &Bs[(w * 32 + c * 16) * 32]);
    }
    __syncthreads();

    bf16x8 af[4], bf[4];
#pragma unroll
    for (int i = 0; i < 4; ++i) {
      af[i] = *(const bf16x8*)&As[(wm * 64 + i * 16 + l16) * 32 + quad * 8];
      bf[i] = *(const bf16x8*)&Bs[(wn * 64 + i * 16 + l16) * 32 + quad * 8];
    }
#pragma unroll
    for (int i = 0; i < 4; ++i)
#pragma unroll
      for (int j = 0; j < 4; ++j)
        acc[i][j] = MFMA_BF16(af[i], bf[j], acc[i][j]);
    __syncthreads();
  }

  if (vTp != nullptr && n0 >= 2560) {
    // v-columns -> vT[b][kv][s]; rows here are b*2048+s with 4 consecutive s per lane
#pragma unroll
    for (int i = 0; i < 4; ++i) {
      const int row = m0 + wm * 64 + i * 16 + quad * 4;
      const int bb = row >> 11, s = row & 2047;
#pragma unroll
      for (int j = 0; j < 4; ++j) {
        const int col = n0 + wn * 64 + j * 16 + l16;
        const float bv = bias[col];
        union { bf16_t h[4]; ushort4 u; } cv;
#pragma unroll
        for (int r = 0; r < 4; ++r) cv.h[r] = __float2bfloat16(acc[i][j][r] + bv);
        *(ushort4*)&vTp[((size_t)bb * 512 + (col - 2560)) * 2048 + s] = cv.u;
      }
    }
    return;
  }

#pragma unroll
  for (int i = 0; i < 4; ++i) {
    const int row = m0 + wm * 64 + i * 16 + quad * 4;
#pragma unroll
    for (int j = 0; j < 4; ++j) {
      const int col = n0 + wn * 64 + j * 16 + l16;
      const float bv = bias[col];
#pragma unroll
      for (int r = 0; r < 4; ++r) {
        const float val = acc[i][j][r] + bv;
        if constexpr (__is_same(TOUT, float)) {
          C[(size_t)(row + r) * N + col] = val;
        } else {
          C[(size_t)(row + r) * N + col] = __float2bfloat16(val);
        }
      }
    }
  }
}

// ---------------- GQA flash attention (v5: K/V LDS double-buffer, 1 barrier/iter) ----------
// QKV: [B*S][3072] bf16 (q at col h*64, Wq pre-scaled by 0.125*log2e; k at 2048+g*64)
// VT: [B*512][2048] bf16 (row b*512+g*64+d, col s); O: [B*S][2048] bf16
// grid (S/128, NH, B) = 1024 blocks; 256 threads; wave owns 32 q rows.
// LDS tiles: 64-elem rows, 16B chunks XOR-swizzled: phys_chunk = chunk ^ (row&7).
// Dbuf: stage iter i+1 right after the single barrier; the barrier's vmcnt(0) drain
// covers loads issued a whole compute-phase earlier -> near-free.
__global__ __launch_bounds__(256, 3) void gqa_attn(
    const bf16_t* __restrict__ QKV, const bf16_t* __restrict__ VT, bf16_t* __restrict__ O) {
  constexpr int S = 2048, HID = 2048, QKVS = 3072, HD = 64;
  const int tid = threadIdx.x;
  const int w = tid >> 6, lane = tid & 63;
  const int quad = lane >> 4, l16 = lane & 15;
  const int q0 = blockIdx.x * 128;
  const int h = blockIdx.y, b = blockIdx.z;
  const int g = h >> 2;  // rep = 4

  __shared__ alignas(16) bf16_t Ks[2][64 * 64];
  __shared__ alignas(16) bf16_t VTs[2][64 * 64];
  __shared__ alignas(16) bf16_t Ps[128 * 64];

  // Q fragments in registers (B-operand layout: n=l16 -> q, k=quad*8+j); pre-scaled
  bf16x8 qf[2][2];
#pragma unroll
  for (int mt = 0; mt < 2; ++mt)
#pragma unroll
    for (int ks = 0; ks < 2; ++ks)
      qf[mt][ks] = *(const bf16x8*)&QKV[(size_t)(b * S + q0 + w * 32 + mt * 16 + l16) * QKVS +
                                        h * HD + ks * 32 + quad * 8];

  const int rr = lane >> 3, c7 = lane & 7;
  const int scol = (c7 ^ rr) * 8;  // swizzled SOURCE column so LDS dest lands swizzled
  const int sx = l16 & 7;

  const bf16_t* Kbase = QKV + (size_t)b * S * QKVS + 2048 + g * HD;
  const bf16_t* Vbase = VT + (size_t)(b * 512 + g * HD) * S;

  f32x4 oacc[2][4] = {};
  f32x4 lacc[2] = {};
  bf16x8 ones;
#pragma unroll
  for (int j = 0; j < 8; ++j) ones[j] = (__bf16)1.0f;

  // stage K/V tile for key-block starting at s0 into buffer `buf`
  auto stage = [&](int s0, int buf) {
#pragma unroll
    for (int cg = 0; cg < 2; ++cg) {
      const int r = w * 16 + cg * 8 + rr;
      async_copy16(Kbase + (size_t)(s0 + r) * QKVS + scol, &Ks[buf][(w * 16 + cg * 8) * 64]);
      async_copy16(Vbase + (size_t)r * S + s0 + scol, &VTs[buf][(w * 16 + cg * 8) * 64]);
    }
  };

  stage(0, 0);

  for (int it = 0; it < S / 64; ++it) {
    const int cur = it & 1;
    __syncthreads();  // drains loads for buf[cur] (issued a full iter ago); protects buf[1-cur]
    if (it + 1 < S / 64) stage((it + 1) * 64, 1 - cur);

    // ---- S^T = K·Q^T (row=kv=quad*4+r, col=q=l16); p=exp2(s); pack(trunc) -> Ps[q][kv] ----
#pragma unroll
    for (int nt = 0; nt < 4; ++nt) {
      bf16x8 kf0 = *(const bf16x8*)&Ks[cur][(nt * 16 + l16) * 64 + ((quad ^ sx) * 8)];
      bf16x8 kf1 = *(const bf16x8*)&Ks[cur][(nt * 16 + l16) * 64 + (((4 + quad) ^ sx) * 8)];
#pragma unroll
      for (int mt = 0; mt < 2; ++mt) {
        f32x4 s = {};
        s = MFMA_BF16(kf0, qf[mt][0], s);
        s = MFMA_BF16(kf1, qf[mt][1], s);
        const float p0 = __builtin_amdgcn_exp2f(s[0]);
        const float p1 = __builtin_amdgcn_exp2f(s[1]);
        const float p2 = __builtin_amdgcn_exp2f(s[2]);
        const float p3 = __builtin_amdgcn_exp2f(s[3]);
        uint2 pk;
        pk.x = __builtin_amdgcn_perm(fbits(p1), fbits(p0), 0x07060302);  // [bf16(p1)|bf16(p0)]
        pk.y = __builtin_amdgcn_perm(fbits(p3), fbits(p2), 0x07060302);
        // logical col = nt*16 + quad*4 (+r): chunk = nt*2+(quad>>1), in-chunk off = (quad&1)*4
        *(uint2*)&Ps[(w * 32 + mt * 16 + l16) * 64 +
                     (((nt * 2 + (quad >> 1)) ^ sx) * 8) + (quad & 1) * 4] = pk;
      }
    }

    // ---- O += P·V; row-sums via ones-B MFMA (sums truncated bf16 P -> bias cancels) ----
#pragma unroll
    for (int kc = 0; kc < 2; ++kc) {
      bf16x8 pf[2];
#pragma unroll
      for (int mt = 0; mt < 2; ++mt) {
        pf[mt] = *(const bf16x8*)&Ps[(w * 32 + mt * 16 + l16) * 64 + (((kc * 4 + quad) ^ sx) * 8)];
        lacc[mt] = MFMA_BF16(pf[mt], ones, lacc[mt]);
      }
#pragma unroll
      for (int dt = 0; dt < 4; ++dt) {
        bf16x8 vf = *(const bf16x8*)&VTs[cur][(dt * 16 + l16) * 64 + (((kc * 4 + quad) ^ sx) * 8)];
#pragma unroll
        for (int mt = 0; mt < 2; ++mt)
          oacc[mt][dt] = MFMA_BF16(pf[mt], vf, oacc[mt][dt]);
      }
    }
  }

  // ---- normalize + store; lacc[mt][r] is lsum for q=mt*16+quad*4+r (same rows as oacc) ----
#pragma unroll
  for (int mt = 0; mt < 2; ++mt) {
    float linv[4];
#pragma unroll
    for (int r = 0; r < 4; ++r) linv[r] = 1.0f / lacc[mt][r];
#pragma unroll
    for (int dt = 0; dt < 4; ++dt)
#pragma unroll
      for (int r = 0; r < 4; ++r)
        O[(size_t)(b * S + q0 + w * 32 + mt * 16 + quad * 4 + r) * HID + h * HD + dt * 16 + l16] =
            __float2bfloat16(oacc[mt][dt][r] * linv[r]);
  }
}

extern "C" void kernel_launch(void* const* d_in, const int* in_sizes, int n_in,
                              void* d_out, int out_size, void* d_ws, size_t ws_size,
                              hipStream_t stream) {
  const float* hidden = (const float*)d_in[0];
  const float* Wq = (const float*)d_in[1];
  const float* bq = (const float*)d_in[2];
  const float* Wk = (const float*)d_in[3];
  const float* bk = (const float*)d_in[4];
  const float* Wv = (const float*)d_in[5];
  const float* bv = (const float*)d_in[6];
  const float* Wo = (const float*)d_in[7];
  const float* bo = (const float*)d_in[8];
  float* out = (float*)d_out;

  constexpr int B = 2, S = 2048, HID = 2048, KV = 512, QKVN = 3072;
  constexpr int M = B * S;  // 4096
  const float c1 = 0.125f * 1.44269504089f;

  char* ws = (char*)d_ws;
  bf16_t* hiddenB = (bf16_t*)ws; ws += (size_t)M * HID * 2;
  bf16_t* WqkvT = (bf16_t*)ws;   ws += (size_t)QKVN * HID * 2;
  bf16_t* WoT = (bf16_t*)ws;     ws += (size_t)HID * HID * 2;
  bf16_t* qkv = (bf16_t*)ws;     ws += (size_t)M * QKVN * 2;
  bf16_t* vT = (bf16_t*)ws;      ws += (size_t)M * KV * 2;
  bf16_t* attn = (bf16_t*)ws;    ws += (size_t)M * HID * 2;
  float* bqkv = (float*)ws;      ws += QKVN * 4;

  // one fused prep launch: cast + 4 weight transposes + bias concat
  prep<<<18444, 256, 0, stream>>>(hidden, Wq, Wk, Wv, Wo, bq, bk, bv,
                                  hiddenB, WqkvT, WoT, bqkv, c1);

  // QKV projection; v-columns written directly to vT (transposed) in the epilogue
  gemm_bt<bf16_t><<<dim3(QKVN / 128, M / 128), 256, 0, stream>>>(
      hiddenB, WqkvT, bqkv, qkv, vT, M, QKVN, HID);

  gqa_attn<<<dim3(S / 128, 32, B), 256, 0, stream>>>(qkv, vT, attn);

  gemm_bt<float><<<dim3(HID / 128, M / 128), 256, 0, stream>>>(
      attn, WoT, bo, out, (bf16_t*)nullptr, M, HID, HID);
}

// Round 6
// 311.718 us; speedup vs baseline: 1.0635x; 1.0377x over previous
//
#include <hip/hip_runtime.h>
#include <hip/hip_bf16.h>
#include <math.h>

typedef __bf16 bf16x8 __attribute__((ext_vector_type(8)));
typedef float f32x4 __attribute__((ext_vector_type(4)));
typedef __hip_bfloat16 bf16_t;

#define MFMA_BF16(a, b, c) __builtin_amdgcn_mfma_f32_16x16x32_bf16((a), (b), (c), 0, 0, 0)

// async global->LDS, 16B per lane; LDS dest = wave-uniform base + lane*16
__device__ __forceinline__ void async_copy16(const bf16_t* g, bf16_t* lds_base) {
  __builtin_amdgcn_global_load_lds(
      (const __attribute__((address_space(1))) unsigned int*)g,
      (__attribute__((address_space(3))) unsigned int*)lds_base,
      16, 0, 0);
}

__device__ __forceinline__ unsigned fbits(float x) { return __builtin_bit_cast(unsigned, x); }

// ---------------- fused prep: cast hidden, transpose 4 weights, concat bias ----------------
// blocks: [0,8192) cast; then 64x64 transpose tiles: Wq [0,1024), Wk [1024,1280),
// Wv [1280,1536), Wo [1536,2560); bias concat [2560,2572). 256 threads.
__global__ __launch_bounds__(256) void prep(
    const float* __restrict__ hidden, const float* __restrict__ Wq, const float* __restrict__ Wk,
    const float* __restrict__ Wv, const float* __restrict__ Wo,
    const float* __restrict__ bq, const float* __restrict__ bk, const float* __restrict__ bv,
    bf16_t* __restrict__ hiddenB, bf16_t* __restrict__ WqkvT, bf16_t* __restrict__ WoT,
    float* __restrict__ bqkv, float c1) {
  __shared__ float tile[64][65];
  int bid = blockIdx.x;
  const int t = threadIdx.x;
  if (bid < 8192) {  // cast hidden f32 -> bf16, float4 per thread
    const int i = bid * 256 + t;
    float4 v = ((const float4*)hidden)[i];
    union { bf16_t h[4]; ushort4 u; } cv;
    cv.h[0] = __float2bfloat16(v.x);
    cv.h[1] = __float2bfloat16(v.y);
    cv.h[2] = __float2bfloat16(v.z);
    cv.h[3] = __float2bfloat16(v.w);
    ((ushort4*)hiddenB)[i] = cv.u;
    return;
  }
  bid -= 8192;
  if (bid >= 2560) {  // bias concat: 12 blocks x 256 = 3072
    const int i = (bid - 2560) * 256 + t;
    float v;
    if (i < 2048) v = bq[i] * c1;
    else if (i < 2560) v = bk[i - 2048];
    else v = bv[i - 2560];
    bqkv[i] = v;
    return;
  }
  // weight transpose: in [2048][C] -> out [C][2048], 64x64 tiles
  const float* src;
  bf16_t* dst;
  int Cc, bx, by;
  float scale = 1.0f;
  if (bid < 1024) { src = Wq; dst = WqkvT; Cc = 2048; bx = bid & 31; by = bid >> 5; scale = c1; }
  else if (bid < 1280) { bid -= 1024; src = Wk; dst = WqkvT + (size_t)2048 * 2048; Cc = 512; bx = bid & 7; by = bid >> 3; }
  else if (bid < 1536) { bid -= 1280; src = Wv; dst = WqkvT + (size_t)2560 * 2048; Cc = 512; bx = bid & 7; by = bid >> 3; }
  else { bid -= 1536; src = Wo; dst = WoT; Cc = 2048; bx = bid & 31; by = bid >> 5; }
  const int tx = t & 63, ty = t >> 6;
  const int c0 = bx * 64, r0 = by * 64;
#pragma unroll
  for (int i = ty; i < 64; i += 4)
    tile[i][tx] = src[(size_t)(r0 + i) * Cc + c0 + tx];
  __syncthreads();
#pragma unroll
  for (int i = ty; i < 64; i += 4)
    dst[(size_t)(c0 + i) * 2048 + r0 + tx] = __float2bfloat16(tile[tx][i] * scale);
}

// ---------------- GEMM: C[M,N] = A[M,K] @ Bt[N,K]^T + bias ----------------
// If vTp != nullptr, blocks with n0 >= 2560 write vT[b][col-2560][s] instead of C
// (v-columns of the QKV projection go straight to the transposed layout attention needs).
// launch_bounds(256,3): cap VGPR ~170 -> 3 blocks/CU (m97 structure ran at 164 VGPR).
template <typename TOUT>
__global__ __launch_bounds__(256, 3) void gemm_bt(
    const bf16_t* __restrict__ A, const bf16_t* __restrict__ Bt,
    const float* __restrict__ bias, TOUT* __restrict__ C, bf16_t* __restrict__ vTp,
    int M, int N, int K) {
  __shared__ alignas(16) bf16_t As[128 * 32];
  __shared__ alignas(16) bf16_t Bs[128 * 32];

  const int tid = threadIdx.x;
  const int w = tid >> 6, lane = tid & 63;
  const int quad = lane >> 4, l16 = lane & 15;
  const int wm = w >> 1, wn = w & 1;
  const int m0 = blockIdx.y * 128, n0 = blockIdx.x * 128;

  f32x4 acc[4][4] = {};

  const int srow = lane >> 2;
  const int scol = (lane & 3) * 8;

  for (int k0 = 0; k0 < K; k0 += 32) {
#pragma unroll
    for (int c = 0; c < 2; ++c) {
      const int r = w * 32 + c * 16 + srow;
      async_copy16(A + (size_t)(m0 + r) * K + k0 + scol, &As[(w * 32 + c * 16) * 32]);
      async_copy16(Bt + (size_t)(n0 + r) * K + k0 + scol, &Bs[(w * 32 + c * 16) * 32]);
    }
    __syncthreads();

    bf16x8 af[4], bf[4];
#pragma unroll
    for (int i = 0; i < 4; ++i) {
      af[i] = *(const bf16x8*)&As[(wm * 64 + i * 16 + l16) * 32 + quad * 8];
      bf[i] = *(const bf16x8*)&Bs[(wn * 64 + i * 16 + l16) * 32 + quad * 8];
    }
#pragma unroll
    for (int i = 0; i < 4; ++i)
#pragma unroll
      for (int j = 0; j < 4; ++j)
        acc[i][j] = MFMA_BF16(af[i], bf[j], acc[i][j]);
    __syncthreads();
  }

  if (vTp != nullptr && n0 >= 2560) {
    // v-columns -> vT[b][kv][s]; rows here are b*2048+s with 4 consecutive s per lane
#pragma unroll
    for (int i = 0; i < 4; ++i) {
      const int row = m0 + wm * 64 + i * 16 + quad * 4;
      const int bb = row >> 11, s = row & 2047;
#pragma unroll
      for (int j = 0; j < 4; ++j) {
        const int col = n0 + wn * 64 + j * 16 + l16;
        const float bv = bias[col];
        union { bf16_t h[4]; ushort4 u; } cv;
#pragma unroll
        for (int r = 0; r < 4; ++r) cv.h[r] = __float2bfloat16(acc[i][j][r] + bv);
        *(ushort4*)&vTp[((size_t)bb * 512 + (col - 2560)) * 2048 + s] = cv.u;
      }
    }
    return;
  }

#pragma unroll
  for (int i = 0; i < 4; ++i) {
    const int row = m0 + wm * 64 + i * 16 + quad * 4;
#pragma unroll
    for (int j = 0; j < 4; ++j) {
      const int col = n0 + wn * 64 + j * 16 + l16;
      const float bv = bias[col];
#pragma unroll
      for (int r = 0; r < 4; ++r) {
        const float val = acc[i][j][r] + bv;
        if constexpr (__is_same(TOUT, float)) {
          C[(size_t)(row + r) * N + col] = val;
        } else {
          C[(size_t)(row + r) * N + col] = __float2bfloat16(val);
        }
      }
    }
  }
}

// ---------------- GQA flash attention (v3 structure: best measured — 87.6us) ----------------
// QKV: [B*S][3072] bf16 (q at col h*64, Wq pre-scaled by 0.125*log2e; k at 2048+g*64)
// VT: [B*512][2048] bf16 (row b*512+g*64+d, col s); O: [B*S][2048] bf16
// grid (S/128, NH, B) = 1024 blocks = 4/CU; 256 threads; wave owns 32 q rows.
// LDS tiles: 64-elem rows, 16B chunks XOR-swizzled: phys_chunk = chunk ^ (row&7).
// NOTE (R4/R5): latency-bound — 4 blocks/CU beats bigger tiles (R4: 2/CU, +1.4us) and
// beats K/V dbuf at 48KB (R5: 3/CU, +13us). Keep 32KB LDS + 2 barriers.
__global__ __launch_bounds__(256, 4) void gqa_attn(
    const bf16_t* __restrict__ QKV, const bf16_t* __restrict__ VT, bf16_t* __restrict__ O) {
  constexpr int S = 2048, HID = 2048, QKVS = 3072, HD = 64;
  const int tid = threadIdx.x;
  const int w = tid >> 6, lane = tid & 63;
  const int quad = lane >> 4, l16 = lane & 15;
  const int q0 = blockIdx.x * 128;
  const int h = blockIdx.y, b = blockIdx.z;
  const int g = h >> 2;  // rep = 4

  __shared__ alignas(16) bf16_t Ks[64 * 64];
  __shared__ alignas(16) bf16_t VTs[64 * 64];
  __shared__ alignas(16) bf16_t Ps[128 * 64];

  // Q fragments in registers (B-operand layout: n=l16 -> q, k=quad*8+j); pre-scaled
  bf16x8 qf[2][2];
#pragma unroll
  for (int mt = 0; mt < 2; ++mt)
#pragma unroll
    for (int ks = 0; ks < 2; ++ks)
      qf[mt][ks] = *(const bf16x8*)&QKV[(size_t)(b * S + q0 + w * 32 + mt * 16 + l16) * QKVS +
                                        h * HD + ks * 32 + quad * 8];

  const int rr = lane >> 3, c7 = lane & 7;
  const int scol = (c7 ^ rr) * 8;  // swizzled SOURCE column so LDS dest lands swizzled
  const int sx = l16 & 7;

  const bf16_t* Kbase = QKV + (size_t)b * S * QKVS + 2048 + g * HD;
  const bf16_t* Vbase = VT + (size_t)(b * 512 + g * HD) * S;

  f32x4 oacc[2][4] = {};
  f32x4 lacc[2] = {};
  bf16x8 ones;
#pragma unroll
  for (int j = 0; j < 8; ++j) ones[j] = (__bf16)1.0f;

  for (int s0 = 0; s0 < S; s0 += 64) {
    __syncthreads();
#pragma unroll
    for (int cg = 0; cg < 2; ++cg) {
      const int r = w * 16 + cg * 8 + rr;
      async_copy16(Kbase + (size_t)(s0 + r) * QKVS + scol, &Ks[(w * 16 + cg * 8) * 64]);
      async_copy16(Vbase + (size_t)r * S + s0 + scol, &VTs[(w * 16 + cg * 8) * 64]);
    }
    __syncthreads();

    // ---- S^T = K·Q^T (row=kv=quad*4+r, col=q=l16); p=exp2(s); pack(trunc) -> Ps[q][kv] ----
#pragma unroll
    for (int nt = 0; nt < 4; ++nt) {
      bf16x8 kf0 = *(const bf16x8*)&Ks[(nt * 16 + l16) * 64 + ((quad ^ sx) * 8)];
      bf16x8 kf1 = *(const bf16x8*)&Ks[(nt * 16 + l16) * 64 + (((4 + quad) ^ sx) * 8)];
#pragma unroll
      for (int mt = 0; mt < 2; ++mt) {
        f32x4 s = {};
        s = MFMA_BF16(kf0, qf[mt][0], s);
        s = MFMA_BF16(kf1, qf[mt][1], s);
        const float p0 = __builtin_amdgcn_exp2f(s[0]);
        const float p1 = __builtin_amdgcn_exp2f(s[1]);
        const float p2 = __builtin_amdgcn_exp2f(s[2]);
        const float p3 = __builtin_amdgcn_exp2f(s[3]);
        uint2 pk;
        pk.x = __builtin_amdgcn_perm(fbits(p1), fbits(p0), 0x07060302);  // [bf16(p1)|bf16(p0)]
        pk.y = __builtin_amdgcn_perm(fbits(p3), fbits(p2), 0x07060302);
        // logical col = nt*16 + quad*4 (+r): chunk = nt*2+(quad>>1), in-chunk off = (quad&1)*4
        *(uint2*)&Ps[(w * 32 + mt * 16 + l16) * 64 +
                     (((nt * 2 + (quad >> 1)) ^ sx) * 8) + (quad & 1) * 4] = pk;
      }
    }

    // ---- O += P·V; row-sums via ones-B MFMA (sums truncated bf16 P -> bias cancels) ----
#pragma unroll
    for (int kc = 0; kc < 2; ++kc) {
      bf16x8 pf[2];
#pragma unroll
      for (int mt = 0; mt < 2; ++mt) {
        pf[mt] = *(const bf16x8*)&Ps[(w * 32 + mt * 16 + l16) * 64 + (((kc * 4 + quad) ^ sx) * 8)];
        lacc[mt] = MFMA_BF16(pf[mt], ones, lacc[mt]);
      }
#pragma unroll
      for (int dt = 0; dt < 4; ++dt) {
        bf16x8 vf = *(const bf16x8*)&VTs[(dt * 16 + l16) * 64 + (((kc * 4 + quad) ^ sx) * 8)];
#pragma unroll
        for (int mt = 0; mt < 2; ++mt)
          oacc[mt][dt] = MFMA_BF16(pf[mt], vf, oacc[mt][dt]);
      }
    }
  }

  // ---- normalize + store; lacc[mt][r] is lsum for q=mt*16+quad*4+r (same rows as oacc) ----
#pragma unroll
  for (int mt = 0; mt < 2; ++mt) {
    float linv[4];
#pragma unroll
    for (int r = 0; r < 4; ++r) linv[r] = 1.0f / lacc[mt][r];
#pragma unroll
    for (int dt = 0; dt < 4; ++dt)
#pragma unroll
      for (int r = 0; r < 4; ++r)
        O[(size_t)(b * S + q0 + w * 32 + mt * 16 + quad * 4 + r) * HID + h * HD + dt * 16 + l16] =
            __float2bfloat16(oacc[mt][dt][r] * linv[r]);
  }
}

extern "C" void kernel_launch(void* const* d_in, const int* in_sizes, int n_in,
                              void* d_out, int out_size, void* d_ws, size_t ws_size,
                              hipStream_t stream) {
  const float* hidden = (const float*)d_in[0];
  const float* Wq = (const float*)d_in[1];
  const float* bq = (const float*)d_in[2];
  const float* Wk = (const float*)d_in[3];
  const float* bk = (const float*)d_in[4];
  const float* Wv = (const float*)d_in[5];
  const float* bv = (const float*)d_in[6];
  const float* Wo = (const float*)d_in[7];
  const float* bo = (const float*)d_in[8];
  float* out = (float*)d_out;

  constexpr int B = 2, S = 2048, HID = 2048, KV = 512, QKVN = 3072;
  constexpr int M = B * S;  // 4096
  const float c1 = 0.125f * 1.44269504089f;

  char* ws = (char*)d_ws;
  bf16_t* hiddenB = (bf16_t*)ws; ws += (size_t)M * HID * 2;
  bf16_t* WqkvT = (bf16_t*)ws;   ws += (size_t)QKVN * HID * 2;
  bf16_t* WoT = (bf16_t*)ws;     ws += (size_t)HID * HID * 2;
  bf16_t* qkv = (bf16_t*)ws;     ws += (size_t)M * QKVN * 2;
  bf16_t* vT = (bf16_t*)ws;      ws += (size_t)M * KV * 2;
  bf16_t* attn = (bf16_t*)ws;    ws += (size_t)M * HID * 2;
  float* bqkv = (float*)ws;      ws += QKVN * 4;

  // one fused prep launch: cast + 4 weight transposes (64x64 tiles) + bias concat
  prep<<<8192 + 2560 + 12, 256, 0, stream>>>(hidden, Wq, Wk, Wv, Wo, bq, bk, bv,
                                             hiddenB, WqkvT, WoT, bqkv, c1);

  // QKV projection; v-columns written directly to vT (transposed) in the epilogue
  gemm_bt<bf16_t><<<dim3(QKVN / 128, M / 128), 256, 0, stream>>>(
      hiddenB, WqkvT, bqkv, qkv, vT, M, QKVN, HID);

  gqa_attn<<<dim3(S / 128, 32, B), 256, 0, stream>>>(qkv, vT, attn);

  gemm_bt<float><<<dim3(HID / 128, M / 128), 256, 0, stream>>>(
      attn, WoT, bo, out, (bf16_t*)nullptr, M, HID, HID);
}

// Round 7
// 311.102 us; speedup vs baseline: 1.0656x; 1.0020x over previous
//
#include <hip/hip_runtime.h>
#include <hip/hip_bf16.h>
#include <math.h>

typedef __bf16 bf16x8 __attribute__((ext_vector_type(8)));
typedef float f32x4 __attribute__((ext_vector_type(4)));
typedef __hip_bfloat16 bf16_t;

#define MFMA_BF16(a, b, c) __builtin_amdgcn_mfma_f32_16x16x32_bf16((a), (b), (c), 0, 0, 0)

// async global->LDS, 16B per lane; LDS dest = wave-uniform base + lane*16
__device__ __forceinline__ void async_copy16(const bf16_t* g, bf16_t* lds_base) {
  __builtin_amdgcn_global_load_lds(
      (const __attribute__((address_space(1))) unsigned int*)g,
      (__attribute__((address_space(3))) unsigned int*)lds_base,
      16, 0, 0);
}

__device__ __forceinline__ unsigned fbits(float x) { return __builtin_bit_cast(unsigned, x); }

// ---------------- fused prep: cast hidden, transpose 4 weights, concat bias ----------------
__global__ __launch_bounds__(256) void prep(
    const float* __restrict__ hidden, const float* __restrict__ Wq, const float* __restrict__ Wk,
    const float* __restrict__ Wv, const float* __restrict__ Wo,
    const float* __restrict__ bq, const float* __restrict__ bk, const float* __restrict__ bv,
    bf16_t* __restrict__ hiddenB, bf16_t* __restrict__ WqkvT, bf16_t* __restrict__ WoT,
    float* __restrict__ bqkv, float c1) {
  __shared__ float tile[64][65];
  int bid = blockIdx.x;
  const int t = threadIdx.x;
  if (bid < 8192) {  // cast hidden f32 -> bf16, float4 per thread
    const int i = bid * 256 + t;
    float4 v = ((const float4*)hidden)[i];
    union { bf16_t h[4]; ushort4 u; } cv;
    cv.h[0] = __float2bfloat16(v.x);
    cv.h[1] = __float2bfloat16(v.y);
    cv.h[2] = __float2bfloat16(v.z);
    cv.h[3] = __float2bfloat16(v.w);
    ((ushort4*)hiddenB)[i] = cv.u;
    return;
  }
  bid -= 8192;
  if (bid >= 2560) {  // bias concat: 12 blocks x 256 = 3072
    const int i = (bid - 2560) * 256 + t;
    float v;
    if (i < 2048) v = bq[i] * c1;
    else if (i < 2560) v = bk[i - 2048];
    else v = bv[i - 2560];
    bqkv[i] = v;
    return;
  }
  // weight transpose: in [2048][C] -> out [C][2048], 64x64 tiles
  const float* src;
  bf16_t* dst;
  int Cc, bx, by;
  float scale = 1.0f;
  if (bid < 1024) { src = Wq; dst = WqkvT; Cc = 2048; bx = bid & 31; by = bid >> 5; scale = c1; }
  else if (bid < 1280) { bid -= 1024; src = Wk; dst = WqkvT + (size_t)2048 * 2048; Cc = 512; bx = bid & 7; by = bid >> 3; }
  else if (bid < 1536) { bid -= 1280; src = Wv; dst = WqkvT + (size_t)2560 * 2048; Cc = 512; bx = bid & 7; by = bid >> 3; }
  else { bid -= 1536; src = Wo; dst = WoT; Cc = 2048; bx = bid & 31; by = bid >> 5; }
  const int tx = t & 63, ty = t >> 6;
  const int c0 = bx * 64, r0 = by * 64;
#pragma unroll
  for (int i = ty; i < 64; i += 4)
    tile[i][tx] = src[(size_t)(r0 + i) * Cc + c0 + tx];
  __syncthreads();
#pragma unroll
  for (int i = ty; i < 64; i += 4)
    dst[(size_t)(c0 + i) * 2048 + r0 + tx] = __float2bfloat16(tile[tx][i] * scale);
}

// ---------------- GEMM: C[M,N] = A[M,K] @ Bt[N,K]^T + bias ----------------
// v7: BK=64 (halves barrier/vmcnt-drain count vs BK=32; LDS 32KB keeps 3 blocks/CU —
// avoids m132's BK=128 occupancy trap). 128B LDS rows -> XOR chunk swizzle
// (phys_chunk = chunk ^ (row&7)) applied at the staging SOURCE address.
// K-halves processed sequentially reusing af/bf regs to hold VGPR ~constant.
// If vTp != nullptr, blocks with n0 >= 2560 write vT[b][col-2560][s] instead of C.
template <typename TOUT>
__global__ __launch_bounds__(256, 3) void gemm_bt(
    const bf16_t* __restrict__ A, const bf16_t* __restrict__ Bt,
    const float* __restrict__ bias, TOUT* __restrict__ C, bf16_t* __restrict__ vTp,
    int M, int N, int K) {
  __shared__ alignas(16) bf16_t As[128 * 64];
  __shared__ alignas(16) bf16_t Bs[128 * 64];

  const int tid = threadIdx.x;
  const int w = tid >> 6, lane = tid & 63;
  const int quad = lane >> 4, l16 = lane & 15;
  const int wm = w >> 1, wn = w & 1;
  const int m0 = blockIdx.y * 128, n0 = blockIdx.x * 128;

  f32x4 acc[4][4] = {};

  const int rr = lane >> 3;                 // row within 8-row staging chunk
  const int scol = ((lane & 7) ^ rr) * 8;   // swizzled SOURCE col (bf16 units)
  const int sx = l16 & 7;                   // row&7 for fragment reads

  for (int k0 = 0; k0 < K; k0 += 64) {
    __syncthreads();
#pragma unroll
    for (int c = 0; c < 4; ++c) {
      const int r = w * 32 + c * 8 + rr;
      async_copy16(A + (size_t)(m0 + r) * K + k0 + scol, &As[(w * 32 + c * 8) * 64]);
      async_copy16(Bt + (size_t)(n0 + r) * K + k0 + scol, &Bs[(w * 32 + c * 8) * 64]);
    }
    __syncthreads();

#pragma unroll
    for (int kh = 0; kh < 2; ++kh) {
      bf16x8 af[4], bf[4];
#pragma unroll
      for (int i = 0; i < 4; ++i) {
        af[i] = *(const bf16x8*)&As[(wm * 64 + i * 16 + l16) * 64 + (((kh * 4 + quad) ^ sx) * 8)];
        bf[i] = *(const bf16x8*)&Bs[(wn * 64 + i * 16 + l16) * 64 + (((kh * 4 + quad) ^ sx) * 8)];
      }
#pragma unroll
      for (int i = 0; i < 4; ++i)
#pragma unroll
        for (int j = 0; j < 4; ++j)
          acc[i][j] = MFMA_BF16(af[i], bf[j], acc[i][j]);
    }
  }

  if (vTp != nullptr && n0 >= 2560) {
    // v-columns -> vT[b][kv][s]; rows here are b*2048+s with 4 consecutive s per lane
#pragma unroll
    for (int i = 0; i < 4; ++i) {
      const int row = m0 + wm * 64 + i * 16 + quad * 4;
      const int bb = row >> 11, s = row & 2047;
#pragma unroll
      for (int j = 0; j < 4; ++j) {
        const int col = n0 + wn * 64 + j * 16 + l16;
        const float bv = bias[col];
        union { bf16_t h[4]; ushort4 u; } cv;
#pragma unroll
        for (int r = 0; r < 4; ++r) cv.h[r] = __float2bfloat16(acc[i][j][r] + bv);
        *(ushort4*)&vTp[((size_t)bb * 512 + (col - 2560)) * 2048 + s] = cv.u;
      }
    }
    return;
  }

#pragma unroll
  for (int i = 0; i < 4; ++i) {
    const int row = m0 + wm * 64 + i * 16 + quad * 4;
#pragma unroll
    for (int j = 0; j < 4; ++j) {
      const int col = n0 + wn * 64 + j * 16 + l16;
      const float bv = bias[col];
#pragma unroll
      for (int r = 0; r < 4; ++r) {
        const float val = acc[i][j][r] + bv;
        if constexpr (__is_same(TOUT, float)) {
          C[(size_t)(row + r) * N + col] = val;
        } else {
          C[(size_t)(row + r) * N + col] = __float2bfloat16(val);
        }
      }
    }
  }
}

// ---------------- GQA flash attention (v7: paired heads share K/V tiles) ----------------
// QKV: [B*S][3072] bf16 (q at col h*64, Wq pre-scaled by 0.125*log2e; k at 2048+g*64)
// VT: [B*512][2048] bf16 (row b*512+g*64+d, col s); O: [B*S][2048] bf16
// grid (S/64, NH/2, B) = 1024 blocks = 4/CU; 256 threads. Block covers 64 q-rows x 2 heads
// (same KV group: h = hp*2+(w&1), g = hp>>1) -> K/V staging serves 2 heads (half traffic).
// Wave owns 32 q rows of one head — per-wave work identical to v3 (best measured point).
// LDS tiles: 64-elem rows, 16B chunks XOR-swizzled: phys_chunk = chunk ^ (row&7).
// NOTE (R4/R5): latency-bound — keep 32KB LDS, 4 blocks/CU, 2 barriers/iter.
__global__ __launch_bounds__(256, 4) void gqa_attn(
    const bf16_t* __restrict__ QKV, const bf16_t* __restrict__ VT, bf16_t* __restrict__ O) {
  constexpr int S = 2048, HID = 2048, QKVS = 3072, HD = 64;
  const int tid = threadIdx.x;
  const int w = tid >> 6, lane = tid & 63;
  const int quad = lane >> 4, l16 = lane & 15;
  const int hp = blockIdx.y, b = blockIdx.z;
  const int h = hp * 2 + (w & 1);       // wave's head
  const int g = hp >> 1;                // shared KV group (rep=4: heads 4g..4g+3)
  const int q0 = blockIdx.x * 64 + (w >> 1) * 32;  // wave's 32 q rows

  __shared__ alignas(16) bf16_t Ks[64 * 64];
  __shared__ alignas(16) bf16_t VTs[64 * 64];
  __shared__ alignas(16) bf16_t Ps[128 * 64];

  // Q fragments in registers (B-operand layout: n=l16 -> q, k=quad*8+j); pre-scaled
  bf16x8 qf[2][2];
#pragma unroll
  for (int mt = 0; mt < 2; ++mt)
#pragma unroll
    for (int ks = 0; ks < 2; ++ks)
      qf[mt][ks] = *(const bf16x8*)&QKV[(size_t)(b * S + q0 + mt * 16 + l16) * QKVS +
                                        h * HD + ks * 32 + quad * 8];

  const int rr = lane >> 3, c7 = lane & 7;
  const int scol = (c7 ^ rr) * 8;  // swizzled SOURCE column so LDS dest lands swizzled
  const int sx = l16 & 7;

  const bf16_t* Kbase = QKV + (size_t)b * S * QKVS + 2048 + g * HD;
  const bf16_t* Vbase = VT + (size_t)(b * 512 + g * HD) * S;

  f32x4 oacc[2][4] = {};
  f32x4 lacc[2] = {};
  bf16x8 ones;
#pragma unroll
  for (int j = 0; j < 8; ++j) ones[j] = (__bf16)1.0f;

  for (int s0 = 0; s0 < S; s0 += 64) {
    __syncthreads();
#pragma unroll
    for (int cg = 0; cg < 2; ++cg) {
      const int r = w * 16 + cg * 8 + rr;  // 4 waves cover kv rows 0..63
      async_copy16(Kbase + (size_t)(s0 + r) * QKVS + scol, &Ks[(w * 16 + cg * 8) * 64]);
      async_copy16(Vbase + (size_t)r * S + s0 + scol, &VTs[(w * 16 + cg * 8) * 64]);
    }
    __syncthreads();

    // ---- S^T = K·Q^T (row=kv=quad*4+r, col=q=l16); p=exp2(s); pack(trunc) -> Ps[q][kv] ----
#pragma unroll
    for (int nt = 0; nt < 4; ++nt) {
      bf16x8 kf0 = *(const bf16x8*)&Ks[(nt * 16 + l16) * 64 + ((quad ^ sx) * 8)];
      bf16x8 kf1 = *(const bf16x8*)&Ks[(nt * 16 + l16) * 64 + (((4 + quad) ^ sx) * 8)];
#pragma unroll
      for (int mt = 0; mt < 2; ++mt) {
        f32x4 s = {};
        s = MFMA_BF16(kf0, qf[mt][0], s);
        s = MFMA_BF16(kf1, qf[mt][1], s);
        const float p0 = __builtin_amdgcn_exp2f(s[0]);
        const float p1 = __builtin_amdgcn_exp2f(s[1]);
        const float p2 = __builtin_amdgcn_exp2f(s[2]);
        const float p3 = __builtin_amdgcn_exp2f(s[3]);
        uint2 pk;
        pk.x = __builtin_amdgcn_perm(fbits(p1), fbits(p0), 0x07060302);  // [bf16(p1)|bf16(p0)]
        pk.y = __builtin_amdgcn_perm(fbits(p3), fbits(p2), 0x07060302);
        // logical col = nt*16 + quad*4 (+r): chunk = nt*2+(quad>>1), in-chunk off = (quad&1)*4
        *(uint2*)&Ps[(w * 32 + mt * 16 + l16) * 64 +
                     (((nt * 2 + (quad >> 1)) ^ sx) * 8) + (quad & 1) * 4] = pk;
      }
    }

    // ---- O += P·V; row-sums via ones-B MFMA (sums truncated bf16 P -> bias cancels) ----
#pragma unroll
    for (int kc = 0; kc < 2; ++kc) {
      bf16x8 pf[2];
#pragma unroll
      for (int mt = 0; mt < 2; ++mt) {
        pf[mt] = *(const bf16x8*)&Ps[(w * 32 + mt * 16 + l16) * 64 + (((kc * 4 + quad) ^ sx) * 8)];
        lacc[mt] = MFMA_BF16(pf[mt], ones, lacc[mt]);
      }
#pragma unroll
      for (int dt = 0; dt < 4; ++dt) {
        bf16x8 vf = *(const bf16x8*)&VTs[(dt * 16 + l16) * 64 + (((kc * 4 + quad) ^ sx) * 8)];
#pragma unroll
        for (int mt = 0; mt < 2; ++mt)
          oacc[mt][dt] = MFMA_BF16(pf[mt], vf, oacc[mt][dt]);
      }
    }
  }

  // ---- normalize + store; lacc[mt][r] is lsum for q=mt*16+quad*4+r (same rows as oacc) ----
#pragma unroll
  for (int mt = 0; mt < 2; ++mt) {
    float linv[4];
#pragma unroll
    for (int r = 0; r < 4; ++r) linv[r] = 1.0f / lacc[mt][r];
#pragma unroll
    for (int dt = 0; dt < 4; ++dt)
#pragma unroll
      for (int r = 0; r < 4; ++r)
        O[(size_t)(b * S + q0 + mt * 16 + quad * 4 + r) * HID + h * HD + dt * 16 + l16] =
            __float2bfloat16(oacc[mt][dt][r] * linv[r]);
  }
}

extern "C" void kernel_launch(void* const* d_in, const int* in_sizes, int n_in,
                              void* d_out, int out_size, void* d_ws, size_t ws_size,
                              hipStream_t stream) {
  const float* hidden = (const float*)d_in[0];
  const float* Wq = (const float*)d_in[1];
  const float* bq = (const float*)d_in[2];
  const float* Wk = (const float*)d_in[3];
  const float* bk = (const float*)d_in[4];
  const float* Wv = (const float*)d_in[5];
  const float* bv = (const float*)d_in[6];
  const float* Wo = (const float*)d_in[7];
  const float* bo = (const float*)d_in[8];
  float* out = (float*)d_out;

  constexpr int B = 2, S = 2048, HID = 2048, KV = 512, QKVN = 3072;
  constexpr int M = B * S;  // 4096
  const float c1 = 0.125f * 1.44269504089f;

  char* ws = (char*)d_ws;
  bf16_t* hiddenB = (bf16_t*)ws; ws += (size_t)M * HID * 2;
  bf16_t* WqkvT = (bf16_t*)ws;   ws += (size_t)QKVN * HID * 2;
  bf16_t* WoT = (bf16_t*)ws;     ws += (size_t)HID * HID * 2;
  bf16_t* qkv = (bf16_t*)ws;     ws += (size_t)M * QKVN * 2;
  bf16_t* vT = (bf16_t*)ws;      ws += (size_t)M * KV * 2;
  bf16_t* attn = (bf16_t*)ws;    ws += (size_t)M * HID * 2;
  float* bqkv = (float*)ws;      ws += QKVN * 4;

  // one fused prep launch: cast + 4 weight transposes (64x64 tiles) + bias concat
  prep<<<8192 + 2560 + 12, 256, 0, stream>>>(hidden, Wq, Wk, Wv, Wo, bq, bk, bv,
                                             hiddenB, WqkvT, WoT, bqkv, c1);

  // QKV projection; v-columns written directly to vT (transposed) in the epilogue
  gemm_bt<bf16_t><<<dim3(QKVN / 128, M / 128), 256, 0, stream>>>(
      hiddenB, WqkvT, bqkv, qkv, vT, M, QKVN, HID);

  gqa_attn<<<dim3(S / 64, 16, B), 256, 0, stream>>>(qkv, vT, attn);

  gemm_bt<float><<<dim3(HID / 128, M / 128), 256, 0, stream>>>(
      attn, WoT, bo, out, (bf16_t*)nullptr, M, HID, HID);
}